// Round 11
// baseline (438.817 us; speedup 1.0000x reference)
//
#include <hip/hip_runtime.h>

typedef unsigned short u16;
typedef unsigned int u32;
typedef __attribute__((ext_vector_type(8))) short short8;
typedef __attribute__((ext_vector_type(4))) float float4v;

static inline int cdiv(int a, int b) { return (a + b - 1) / b; }

__device__ __forceinline__ u16 f2bf(float f) {
    u32 u = __float_as_uint(f);
    u = (u + 0x7fffu + ((u >> 16) & 1u)) >> 16;
    return (u16)u;
}
__device__ __forceinline__ float bf2f(u16 s) {
    return __uint_as_float(((u32)s) << 16);
}

// W ([K][COUT] fp32) -> bf16 hi/lo, k-group-major: wt[(g*COUT + co)*16 + (k&7)]
// h at +0..7, l at +8..15  (g = k>>3). B-frag loads coalesce across co lanes.
__global__ __launch_bounds__(256) void wsplit(
    const float* __restrict__ W, u16* __restrict__ wt, int K, int COUT)
{
    int e = blockIdx.x * 256 + threadIdx.x;
    if (e >= K * COUT) return;
    int kk = e / COUT, co = e % COUT;
    float w = W[e];
    u16 h = f2bf(w);
    u16 l = f2bf(w - bf2f(h));
    size_t base = ((size_t)(kk >> 3) * COUT + co) * 16 + (kk & 7);
    wt[base] = h;
    wt[base + 8] = l;
}

// ------ Layer 1: C_in=1 -> 16. One thread/row; all 27 idx loaded up front ---
__global__ __launch_bounds__(256, 4) void conv_l1(
    const float* __restrict__ feats, const int* __restrict__ nmap,
    const float* __restrict__ W, u16* __restrict__ o, int N)
{
    __shared__ float4 w4[27 * 4];
    for (int i = threadIdx.x; i < 27 * 4; i += 256)
        w4[i] = reinterpret_cast<const float4*>(W)[i];
    __syncthreads();

    const int row = blockIdx.x * 256 + threadIdx.x;
    if (row >= N) return;

    // 27 independent, coalesced idx loads — all in flight together
    int idxv[27];
#pragma unroll
    for (int k = 0; k < 27; ++k)
        idxv[k] = nmap[(size_t)k * N + row];

    float acc[16];
#pragma unroll
    for (int j = 0; j < 16; ++j) acc[j] = 0.f;

#pragma unroll
    for (int k = 0; k < 27; ++k) {
        int idx = idxv[k];
        float v = (idx >= 0) ? feats[idx] : 0.f;
#pragma unroll
        for (int cq = 0; cq < 4; ++cq) {
            float4 w = w4[k * 4 + cq];   // uniform address -> LDS broadcast
            acc[cq * 4 + 0] = fmaf(v, w.x, acc[cq * 4 + 0]);
            acc[cq * 4 + 1] = fmaf(v, w.y, acc[cq * 4 + 1]);
            acc[cq * 4 + 2] = fmaf(v, w.z, acc[cq * 4 + 2]);
            acc[cq * 4 + 3] = fmaf(v, w.w, acc[cq * 4 + 3]);
        }
    }

    // row layout (32 u16): [h0-7, l0-7, h8-15, l8-15]; 4 x 16B coalesced stores
    u16* op = o + (size_t)row * 32;
#pragma unroll
    for (int g = 0; g < 2; ++g) {
        u32 hw[4], lw[4];
#pragma unroll
        for (int p = 0; p < 4; ++p) {
            float v0 = acc[g * 8 + 2 * p], v1 = acc[g * 8 + 2 * p + 1];
            u16 h0 = f2bf(v0), h1 = f2bf(v1);
            hw[p] = (u32)h0 | ((u32)h1 << 16);
            lw[p] = (u32)f2bf(v0 - bf2f(h0)) | ((u32)f2bf(v1 - bf2f(h1)) << 16);
        }
        *reinterpret_cast<uint4*>(op + g * 16) = make_uint4(hw[0], hw[1], hw[2], hw[3]);
        *reinterpret_cast<uint4*>(op + g * 16 + 8) = make_uint4(lw[0], lw[1], lw[2], lw[3]);
    }
}

// ------ 2-wave direct-fragment MFMA gathered GEMM (no LDS, no barriers) -----
// 128 threads = 2 independent waves; wave w owns rows [blk*64 + w*32, +32).
// launch_bounds(128,4): VGPR budget 128. A-frag prefetch DEPTH 3 (gather for
// step s+2 issued at step s -> ~2 steps of latency cover), idx ring depth 4,
// B (L1/L2-resident) depth 2. Fully unrolled K: all indices compile-time.
// x: [row][2*CIN] u16, per 8-k group [h8|l8]. wt: k-group-major (see wsplit).
template<int CIN, int COUT, int KSPLIT, bool BFOUT>
__global__ __launch_bounds__(128, 4) void conv_direct(
    const u16* __restrict__ x, const int* __restrict__ nmap,
    const u16* __restrict__ wt,
    float* __restrict__ outf, u16* __restrict__ o, int N)
{
    constexpr int K = 27 * CIN;
    constexpr int KSTEPS = (K + 31) / 32;
    constexpr int KPER = (KSTEPS + KSPLIT - 1) / KSPLIT;
    static_assert(KPER * KSPLIT >= KSTEPS, "");

    const int lane = threadIdx.x & 63;
    const int wv = threadIdx.x >> 6;
    const int fr = lane & 15;
    const int kc = lane >> 4;
    const int row0 = (blockIdx.x * 2 + wv) * 32;
    const int co0 = blockIdx.y * 32;
    const int ks0 = blockIdx.z * KPER;

    float4v acc[2][2];
#pragma unroll
    for (int i = 0; i < 2; ++i)
#pragma unroll
        for (int j = 0; j < 2; ++j) acc[i][j] = (float4v){0.f, 0.f, 0.f, 0.f};

    int idxq[4][2];
    short8 ah[3][2], al[3][2], bh[2][2], bl[2][2];
    const short8 zero8 = (short8){0, 0, 0, 0, 0, 0, 0, 0};

    auto load_idx = [&](int s, int slot) {
        int kk8 = (ks0 + s) * 32 + kc * 8;
        int koff = kk8 / CIN;
#pragma unroll
        for (int i = 0; i < 2; ++i) {
            int r = row0 + i * 16 + fr;
            idxq[slot][i] = (kk8 < K && r < N) ? nmap[(size_t)koff * N + r] : -1;
        }
    };
    auto load_fragA = [&](int s, int islot, int p) {
        int kk8 = (ks0 + s) * 32 + kc * 8;
        int cg = (kk8 & (CIN - 1)) >> 3;
#pragma unroll
        for (int i = 0; i < 2; ++i) {
            int idx = idxq[islot][i];
            if (idx >= 0) {
                const u16* base = x + (size_t)idx * (2 * CIN) + cg * 16;
                ah[p][i] = *reinterpret_cast<const short8*>(base);
                al[p][i] = *reinterpret_cast<const short8*>(base + 8);
            } else {
                ah[p][i] = zero8;
                al[p][i] = zero8;
            }
        }
    };
    auto load_fragB = [&](int s, int p) {
        int g = (ks0 + s) * 4 + kc;
        bool ok = (g * 8) < K;
#pragma unroll
        for (int j = 0; j < 2; ++j) {
            const u16* bp = wt + ((size_t)g * COUT + (co0 + j * 16 + fr)) * 16;
            bh[p][j] = ok ? *reinterpret_cast<const short8*>(bp) : zero8;
            bl[p][j] = ok ? *reinterpret_cast<const short8*>(bp + 8) : zero8;
        }
    };
    auto mm = [&](int pa, int pb) {
#pragma unroll
        for (int i = 0; i < 2; ++i)
#pragma unroll
            for (int j = 0; j < 2; ++j) {
                acc[i][j] = __builtin_amdgcn_mfma_f32_16x16x32_bf16(ah[pa][i], bh[pb][j], acc[i][j], 0, 0, 0);
                acc[i][j] = __builtin_amdgcn_mfma_f32_16x16x32_bf16(ah[pa][i], bl[pb][j], acc[i][j], 0, 0, 0);
                acc[i][j] = __builtin_amdgcn_mfma_f32_16x16x32_bf16(al[pa][i], bh[pb][j], acc[i][j], 0, 0, 0);
            }
    };

    // prologue: idx 0..3, A-frags 0..1, B-frag 0
    load_idx(0, 0);
    if (KPER > 1) load_idx(1, 1);
    if (KPER > 2) load_idx(2, 2);
    if (KPER > 3) load_idx(3, 3);
    load_fragA(0, 0, 0);
    if (KPER > 1) load_fragA(1, 1, 1);
    load_fragB(0, 0);

#pragma unroll
    for (int s = 0; s < KPER; ++s) {
        if (s + 2 < KPER) load_fragA(s + 2, (s + 2) & 3, (s + 2) % 3);
        if (s + 4 < KPER) load_idx(s + 4, (s + 4) & 3);
        if (s + 1 < KPER) load_fragB(s + 1, (s + 1) & 1);
        mm(s % 3, s & 1);
    }

    // D layout: row=(lane>>4)*4+q, col=lane&15 (m89)
    const int orow0 = row0 + (lane >> 4) * 4;
    const int ocol0 = co0 + fr;
#pragma unroll
    for (int i = 0; i < 2; ++i)
#pragma unroll
        for (int j = 0; j < 2; ++j)
#pragma unroll
            for (int q = 0; q < 4; ++q) {
                int r = orow0 + i * 16 + q;
                int c = ocol0 + j * 16;
                if (r < N) {
                    float v = acc[i][j][q];
                    if constexpr (BFOUT) {
                        u16 h = f2bf(v);
                        size_t base = (size_t)r * (2 * COUT) + ((c >> 3) * 16) + (c & 7);
                        o[base] = h;
                        o[base + 8] = f2bf(v - bf2f(h));
                    } else {
                        outf[(size_t)blockIdx.z * N * COUT + (size_t)r * COUT + c] = v;
                    }
                }
            }
}

// ------ deterministic fixed-order K-split reductions ------
__global__ __launch_bounds__(256) void reduce_f32(
    const float* __restrict__ p, float* __restrict__ out, int m4, int S)
{
    int i = blockIdx.x * 256 + threadIdx.x;
    if (i >= m4) return;
    const float4* p4 = reinterpret_cast<const float4*>(p);
    float4 a = p4[i];
    for (int s = 1; s < S; ++s) {
        float4 v = p4[(size_t)s * m4 + i];
        a.x += v.x; a.y += v.y; a.z += v.z; a.w += v.w;
    }
    reinterpret_cast<float4*>(out)[i] = a;
}
template<int C>
__global__ __launch_bounds__(256) void reduce_bf(
    const float* __restrict__ p, u16* __restrict__ o, int m, int S)
{
    int i = blockIdx.x * 256 + threadIdx.x;
    if (i >= m) return;
    float a = p[i];
    for (int s = 1; s < S; ++s) a += p[(size_t)s * m + i];
    int r = i / C, c = i % C;
    u16 h = f2bf(a);
    size_t base = (size_t)r * (2 * C) + ((c >> 3) * 16) + (c & 7);
    o[base] = h;
    o[base + 8] = f2bf(a - bf2f(h));
}

extern "C" void kernel_launch(void* const* d_in, const int* in_sizes, int n_in,
                              void* d_out, int out_size, void* d_ws, size_t ws_size,
                              hipStream_t stream)
{
    const float* feats = (const float*)d_in[0];
    const float* W1 = (const float*)d_in[1];
    const int*   nm1 = (const int*)d_in[2];
    const float* W2 = (const float*)d_in[3];
    const int*   nm2 = (const int*)d_in[4];
    const float* W3 = (const float*)d_in[5];
    const int*   nm3 = (const int*)d_in[6];
    const float* W4 = (const float*)d_in[7];
    const int*   nm4 = (const int*)d_in[8];
    const float* W5 = (const float*)d_in[9];
    const int*   nm5 = (const int*)d_in[10];

    const int M1 = in_sizes[2] / 27;
    const int M2 = in_sizes[4] / 27;
    const int M3 = in_sizes[6] / 27;
    const int M4 = in_sizes[8] / 27;
    const int M5 = in_sizes[10] / 27;

    u16* x1 = (u16*)d_ws;                        // M1 x 32
    u16* x2 = x1 + (size_t)M1 * 32;              // M2 x 64
    u16* x3 = x2 + (size_t)M2 * 64;              // M3 x 128
    u16* x4 = x3 + (size_t)M3 * 128;             // M4 x 256
    u16* wt2 = x4 + (size_t)M4 * 256;            // 2*432*32
    u16* wt3 = wt2 + 2 * 432 * 32;               // 2*864*64
    u16* wt4 = wt3 + 2 * 864 * 64;               // 2*1728*128
    u16* wt5 = wt4 + 2 * 1728 * 128;             // 2*3456*512
    // partials alias dead regions (p4 on x1: dead after L2; p5 on x2: dead after L3)
    float* p4 = (float*)x1;                      // 2 * M4*128 f32
    float* p5 = (float*)x2;                      // 4 * M5*512 f32

    wsplit<<<cdiv(432 * 32, 256), 256, 0, stream>>>(W2, wt2, 432, 32);
    wsplit<<<cdiv(864 * 64, 256), 256, 0, stream>>>(W3, wt3, 864, 64);
    wsplit<<<cdiv(1728 * 128, 256), 256, 0, stream>>>(W4, wt4, 1728, 128);
    wsplit<<<cdiv(3456 * 512, 256), 256, 0, stream>>>(W5, wt5, 3456, 512);

    conv_l1<<<cdiv(M1, 256), 256, 0, stream>>>(feats, nm1, W1, x1, M1);

    // L2: 16 -> 32, KPER=14
    conv_direct<16, 32, 1, true>
        <<<dim3(cdiv(M2, 64), 1, 1), 128, 0, stream>>>(
            x1, nm2, wt2, nullptr, x2, M2);
    // L3: 32 -> 64, KPER=27
    conv_direct<32, 64, 1, true>
        <<<dim3(cdiv(M3, 64), 2, 1), 128, 0, stream>>>(
            x2, nm3, wt3, nullptr, x3, M3);
    // L4: 64 -> 128, K-split 2 (KPER=27)
    conv_direct<64, 128, 2, false>
        <<<dim3(cdiv(M4, 64), 4, 2), 128, 0, stream>>>(
            x3, nm4, wt4, p4, nullptr, M4);
    reduce_bf<128><<<cdiv(M4 * 128, 256), 256, 0, stream>>>(p4, x4, M4 * 128, 2);
    // L5: 128 -> 512, K-split 4 (KPER=27)
    conv_direct<128, 512, 4, false>
        <<<dim3(cdiv(M5, 64), 16, 4), 128, 0, stream>>>(
            x4, nm5, wt5, p5, nullptr, M5);
    reduce_f32<<<cdiv(M5 * 512 / 4, 256), 256, 0, stream>>>(p5, (float*)d_out, M5 * 512 / 4, 4);
}

// Round 12
// 153.670 us; speedup vs baseline: 2.8556x; 2.8556x over previous
//
#include <hip/hip_runtime.h>

typedef unsigned short u16;
typedef unsigned int u32;
typedef __attribute__((ext_vector_type(8))) short short8;
typedef __attribute__((ext_vector_type(4))) float float4v;

static inline int cdiv(int a, int b) { return (a + b - 1) / b; }

__device__ __forceinline__ u16 f2bf(float f) {
    u32 u = __float_as_uint(f);
    u = (u + 0x7fffu + ((u >> 16) & 1u)) >> 16;
    return (u16)u;
}
__device__ __forceinline__ float bf2f(u16 s) {
    return __uint_as_float(((u32)s) << 16);
}

// W ([K][COUT] fp32) -> bf16 hi/lo, k-group-major: wt[(g*COUT + co)*16 + (k&7)]
// h at +0..7, l at +8..15  (g = k>>3). B-frag loads coalesce across co lanes.
__global__ __launch_bounds__(256) void wsplit(
    const float* __restrict__ W, u16* __restrict__ wt, int K, int COUT)
{
    int e = blockIdx.x * 256 + threadIdx.x;
    if (e >= K * COUT) return;
    int kk = e / COUT, co = e % COUT;
    float w = W[e];
    u16 h = f2bf(w);
    u16 l = f2bf(w - bf2f(h));
    size_t base = ((size_t)(kk >> 3) * COUT + co) * 16 + (kk & 7);
    wt[base] = h;
    wt[base + 8] = l;
}

// ------ Layer 1: C_in=1 -> 16. ONE thread per row, unroll 3 (R7 variant) ----
__global__ __launch_bounds__(256) void conv_l1(
    const float* __restrict__ feats, const int* __restrict__ nmap,
    const float* __restrict__ W, u16* __restrict__ o, int N)
{
    __shared__ float4 w4[27 * 4];
    for (int i = threadIdx.x; i < 27 * 4; i += 256)
        w4[i] = reinterpret_cast<const float4*>(W)[i];
    __syncthreads();

    const int row = blockIdx.x * 256 + threadIdx.x;
    if (row >= N) return;

    float acc[16];
#pragma unroll
    for (int j = 0; j < 16; ++j) acc[j] = 0.f;

#pragma unroll 3
    for (int k = 0; k < 27; ++k) {
        int idx = nmap[(size_t)k * N + row];
        float v = (idx >= 0) ? feats[idx] : 0.f;
#pragma unroll
        for (int cq = 0; cq < 4; ++cq) {
            float4 w = w4[k * 4 + cq];   // uniform address -> LDS broadcast
            acc[cq * 4 + 0] = fmaf(v, w.x, acc[cq * 4 + 0]);
            acc[cq * 4 + 1] = fmaf(v, w.y, acc[cq * 4 + 1]);
            acc[cq * 4 + 2] = fmaf(v, w.z, acc[cq * 4 + 2]);
            acc[cq * 4 + 3] = fmaf(v, w.w, acc[cq * 4 + 3]);
        }
    }

    // row layout (32 u16): [h0-7, l0-7, h8-15, l8-15]; 4 x 16B coalesced stores
    u16* op = o + (size_t)row * 32;
#pragma unroll
    for (int g = 0; g < 2; ++g) {
        u32 hw[4], lw[4];
#pragma unroll
        for (int p = 0; p < 4; ++p) {
            float v0 = acc[g * 8 + 2 * p], v1 = acc[g * 8 + 2 * p + 1];
            u16 h0 = f2bf(v0), h1 = f2bf(v1);
            hw[p] = (u32)h0 | ((u32)h1 << 16);
            lw[p] = (u32)f2bf(v0 - bf2f(h0)) | ((u32)f2bf(v1 - bf2f(h1)) << 16);
        }
        *reinterpret_cast<uint4*>(op + g * 16) = make_uint4(hw[0], hw[1], hw[2], hw[3]);
        *reinterpret_cast<uint4*>(op + g * 16 + 8) = make_uint4(lw[0], lw[1], lw[2], lw[3]);
    }
}

// ------ 2-wave direct-fragment MFMA gathered GEMM (no LDS, no barriers) -----
// 128 threads = 2 independent waves; wave w owns rows [blk*64 + w*32, +32).
// launch_bounds(128,4): VGPR budget 128; depth-2 A frags (VGPR ~60, no spill).
// x: [row][2*CIN] u16, per 8-k group [h8|l8]. wt: k-group-major (see wsplit).
// Wave tile 32x32 (FM=FN=2). Depth-2 frag buffers, depth-3 idx ring,
// fully unrolled K so all buffer indices are compile-time.
template<int CIN, int COUT, int KSPLIT, bool BFOUT>
__global__ __launch_bounds__(128, 4) void conv_direct(
    const u16* __restrict__ x, const int* __restrict__ nmap,
    const u16* __restrict__ wt,
    float* __restrict__ outf, u16* __restrict__ o, int N)
{
    constexpr int K = 27 * CIN;
    constexpr int KSTEPS = (K + 31) / 32;
    constexpr int KPER = (KSTEPS + KSPLIT - 1) / KSPLIT;
    static_assert(KPER * KSPLIT >= KSTEPS, "");

    const int lane = threadIdx.x & 63;
    const int wv = threadIdx.x >> 6;
    const int fr = lane & 15;
    const int kc = lane >> 4;
    const int row0 = (blockIdx.x * 2 + wv) * 32;
    const int co0 = blockIdx.y * 32;
    const int ks0 = blockIdx.z * KPER;

    float4v acc[2][2];
#pragma unroll
    for (int i = 0; i < 2; ++i)
#pragma unroll
        for (int j = 0; j < 2; ++j) acc[i][j] = (float4v){0.f, 0.f, 0.f, 0.f};

    int idxq[3][2];
    short8 ah[2][2], al[2][2], bh[2][2], bl[2][2];
    const short8 zero8 = (short8){0, 0, 0, 0, 0, 0, 0, 0};

    auto load_idx = [&](int s, int slot) {
        int kk8 = (ks0 + s) * 32 + kc * 8;
        int koff = kk8 / CIN;
#pragma unroll
        for (int i = 0; i < 2; ++i) {
            int r = row0 + i * 16 + fr;
            idxq[slot][i] = (kk8 < K && r < N) ? nmap[(size_t)koff * N + r] : -1;
        }
    };
    auto load_frag = [&](int s, int islot, int p) {
        int kk8 = (ks0 + s) * 32 + kc * 8;
        int cg = (kk8 & (CIN - 1)) >> 3;
#pragma unroll
        for (int i = 0; i < 2; ++i) {
            int idx = idxq[islot][i];
            if (idx >= 0) {
                const u16* base = x + (size_t)idx * (2 * CIN) + cg * 16;
                ah[p][i] = *reinterpret_cast<const short8*>(base);
                al[p][i] = *reinterpret_cast<const short8*>(base + 8);
            } else {
                ah[p][i] = zero8;
                al[p][i] = zero8;
            }
        }
        int g = (ks0 + s) * 4 + kc;
        bool ok = (g * 8) < K;
#pragma unroll
        for (int j = 0; j < 2; ++j) {
            const u16* bp = wt + ((size_t)g * COUT + (co0 + j * 16 + fr)) * 16;
            bh[p][j] = ok ? *reinterpret_cast<const short8*>(bp) : zero8;
            bl[p][j] = ok ? *reinterpret_cast<const short8*>(bp + 8) : zero8;
        }
    };
    auto mm = [&](int p) {
#pragma unroll
        for (int i = 0; i < 2; ++i)
#pragma unroll
            for (int j = 0; j < 2; ++j) {
                acc[i][j] = __builtin_amdgcn_mfma_f32_16x16x32_bf16(ah[p][i], bh[p][j], acc[i][j], 0, 0, 0);
                acc[i][j] = __builtin_amdgcn_mfma_f32_16x16x32_bf16(ah[p][i], bl[p][j], acc[i][j], 0, 0, 0);
                acc[i][j] = __builtin_amdgcn_mfma_f32_16x16x32_bf16(al[p][i], bh[p][j], acc[i][j], 0, 0, 0);
            }
    };

    load_idx(0, 0);
    if (KPER > 1) load_idx(1, 1);
    if (KPER > 2) load_idx(2, 2);
    load_frag(0, 0, 0);
#pragma unroll
    for (int s = 0; s < KPER; ++s) {
        if (s + 3 < KPER) load_idx(s + 3, (s + 3) % 3);
        if (s + 1 < KPER) load_frag(s + 1, (s + 1) % 3, (s + 1) & 1);
        mm(s & 1);
    }

    // D layout: row=(lane>>4)*4+q, col=lane&15 (m89)
    const int orow0 = row0 + (lane >> 4) * 4;
    const int ocol0 = co0 + fr;
#pragma unroll
    for (int i = 0; i < 2; ++i)
#pragma unroll
        for (int j = 0; j < 2; ++j)
#pragma unroll
            for (int q = 0; q < 4; ++q) {
                int r = orow0 + i * 16 + q;
                int c = ocol0 + j * 16;
                if (r < N) {
                    float v = acc[i][j][q];
                    if constexpr (BFOUT) {
                        u16 h = f2bf(v);
                        size_t base = (size_t)r * (2 * COUT) + ((c >> 3) * 16) + (c & 7);
                        o[base] = h;
                        o[base + 8] = f2bf(v - bf2f(h));
                    } else {
                        outf[(size_t)blockIdx.z * N * COUT + (size_t)r * COUT + c] = v;
                    }
                }
            }
}

// ------ deterministic fixed-order K-split reductions ------
__global__ __launch_bounds__(256) void reduce_f32(
    const float* __restrict__ p, float* __restrict__ out, int m4, int S)
{
    int i = blockIdx.x * 256 + threadIdx.x;
    if (i >= m4) return;
    const float4* p4 = reinterpret_cast<const float4*>(p);
    float4 a = p4[i];
    for (int s = 1; s < S; ++s) {
        float4 v = p4[(size_t)s * m4 + i];
        a.x += v.x; a.y += v.y; a.z += v.z; a.w += v.w;
    }
    reinterpret_cast<float4*>(out)[i] = a;
}
template<int C>
__global__ __launch_bounds__(256) void reduce_bf(
    const float* __restrict__ p, u16* __restrict__ o, int m, int S)
{
    int i = blockIdx.x * 256 + threadIdx.x;
    if (i >= m) return;
    float a = p[i];
    for (int s = 1; s < S; ++s) a += p[(size_t)s * m + i];
    int r = i / C, c = i % C;
    u16 h = f2bf(a);
    size_t base = (size_t)r * (2 * C) + ((c >> 3) * 16) + (c & 7);
    o[base] = h;
    o[base + 8] = f2bf(a - bf2f(h));
}

extern "C" void kernel_launch(void* const* d_in, const int* in_sizes, int n_in,
                              void* d_out, int out_size, void* d_ws, size_t ws_size,
                              hipStream_t stream)
{
    const float* feats = (const float*)d_in[0];
    const float* W1 = (const float*)d_in[1];
    const int*   nm1 = (const int*)d_in[2];
    const float* W2 = (const float*)d_in[3];
    const int*   nm2 = (const int*)d_in[4];
    const float* W3 = (const float*)d_in[5];
    const int*   nm3 = (const int*)d_in[6];
    const float* W4 = (const float*)d_in[7];
    const int*   nm4 = (const int*)d_in[8];
    const float* W5 = (const float*)d_in[9];
    const int*   nm5 = (const int*)d_in[10];

    const int M1 = in_sizes[2] / 27;
    const int M2 = in_sizes[4] / 27;
    const int M3 = in_sizes[6] / 27;
    const int M4 = in_sizes[8] / 27;
    const int M5 = in_sizes[10] / 27;

    u16* x1 = (u16*)d_ws;                        // M1 x 32
    u16* x2 = x1 + (size_t)M1 * 32;              // M2 x 64
    u16* x3 = x2 + (size_t)M2 * 64;              // M3 x 128
    u16* x4 = x3 + (size_t)M3 * 128;             // M4 x 256
    u16* wt2 = x4 + (size_t)M4 * 256;            // 2*432*32
    u16* wt3 = wt2 + 2 * 432 * 32;               // 2*864*64
    u16* wt4 = wt3 + 2 * 864 * 64;               // 2*1728*128
    u16* wt5 = wt4 + 2 * 1728 * 128;             // 2*3456*512
    // partials alias dead regions (p4 on x1: dead after L2; p5 on x2: dead after L3)
    float* p4 = (float*)x1;                      // 2 * M4*128 f32
    float* p5 = (float*)x2;                      // 4 * M5*512 f32

    wsplit<<<cdiv(432 * 32, 256), 256, 0, stream>>>(W2, wt2, 432, 32);
    wsplit<<<cdiv(864 * 64, 256), 256, 0, stream>>>(W3, wt3, 864, 64);
    wsplit<<<cdiv(1728 * 128, 256), 256, 0, stream>>>(W4, wt4, 1728, 128);
    wsplit<<<cdiv(3456 * 512, 256), 256, 0, stream>>>(W5, wt5, 3456, 512);

    conv_l1<<<cdiv(M1, 256), 256, 0, stream>>>(feats, nm1, W1, x1, M1);

    // L2: 16 -> 32, KPER=14
    conv_direct<16, 32, 1, true>
        <<<dim3(cdiv(M2, 64), 1, 1), 128, 0, stream>>>(
            x1, nm2, wt2, nullptr, x2, M2);
    // L3: 32 -> 64, KPER=27
    conv_direct<32, 64, 1, true>
        <<<dim3(cdiv(M3, 64), 2, 1), 128, 0, stream>>>(
            x2, nm3, wt3, nullptr, x3, M3);
    // L4: 64 -> 128, K-split 2 (KPER=27)
    conv_direct<64, 128, 2, false>
        <<<dim3(cdiv(M4, 64), 4, 2), 128, 0, stream>>>(
            x3, nm4, wt4, p4, nullptr, M4);
    reduce_bf<128><<<cdiv(M4 * 128, 256), 256, 0, stream>>>(p4, x4, M4 * 128, 2);
    // L5: 128 -> 512, K-split 4 (KPER=27)
    conv_direct<128, 512, 4, false>
        <<<dim3(cdiv(M5, 64), 16, 4), 128, 0, stream>>>(
            x4, nm5, wt5, p5, nullptr, M5);
    reduce_f32<<<cdiv(M5 * 512 / 4, 256), 256, 0, stream>>>(p5, (float*)d_out, M5 * 512 / 4, 4);
}

// Round 13
// 150.372 us; speedup vs baseline: 2.9182x; 1.0219x over previous
//
#include <hip/hip_runtime.h>

typedef unsigned short u16;
typedef unsigned int u32;
typedef __attribute__((ext_vector_type(8))) short short8;
typedef __attribute__((ext_vector_type(4))) float float4v;

static inline int cdiv(int a, int b) { return (a + b - 1) / b; }

__device__ __forceinline__ u16 f2bf(float f) {
    u32 u = __float_as_uint(f);
    u = (u + 0x7fffu + ((u >> 16) & 1u)) >> 16;
    return (u16)u;
}
__device__ __forceinline__ float bf2f(u16 s) {
    return __uint_as_float(((u32)s) << 16);
}

// W ([K][COUT] fp32) -> bf16 hi/lo, k-group-major: wt[(g*COUT + co)*16 + (k&7)]
// h at +0..7, l at +8..15  (g = k>>3). B-frag loads coalesce across co lanes.
__global__ __launch_bounds__(256) void wsplit(
    const float* __restrict__ W, u16* __restrict__ wt, int K, int COUT)
{
    int e = blockIdx.x * 256 + threadIdx.x;
    if (e >= K * COUT) return;
    int kk = e / COUT, co = e % COUT;
    float w = W[e];
    u16 h = f2bf(w);
    u16 l = f2bf(w - bf2f(h));
    size_t base = ((size_t)(kk >> 3) * COUT + co) * 16 + (kk & 7);
    wt[base] = h;
    wt[base + 8] = l;
}

// ------ Layer 1: C_in=1 -> 16. ONE thread per row, unroll 3 (R7 variant) ----
__global__ __launch_bounds__(256) void conv_l1(
    const float* __restrict__ feats, const int* __restrict__ nmap,
    const float* __restrict__ W, u16* __restrict__ o, int N)
{
    __shared__ float4 w4[27 * 4];
    for (int i = threadIdx.x; i < 27 * 4; i += 256)
        w4[i] = reinterpret_cast<const float4*>(W)[i];
    __syncthreads();

    const int row = blockIdx.x * 256 + threadIdx.x;
    if (row >= N) return;

    float acc[16];
#pragma unroll
    for (int j = 0; j < 16; ++j) acc[j] = 0.f;

#pragma unroll 3
    for (int k = 0; k < 27; ++k) {
        int idx = nmap[(size_t)k * N + row];
        float v = (idx >= 0) ? feats[idx] : 0.f;
#pragma unroll
        for (int cq = 0; cq < 4; ++cq) {
            float4 w = w4[k * 4 + cq];   // uniform address -> LDS broadcast
            acc[cq * 4 + 0] = fmaf(v, w.x, acc[cq * 4 + 0]);
            acc[cq * 4 + 1] = fmaf(v, w.y, acc[cq * 4 + 1]);
            acc[cq * 4 + 2] = fmaf(v, w.z, acc[cq * 4 + 2]);
            acc[cq * 4 + 3] = fmaf(v, w.w, acc[cq * 4 + 3]);
        }
    }

    // row layout (32 u16): [h0-7, l0-7, h8-15, l8-15]; 4 x 16B coalesced stores
    u16* op = o + (size_t)row * 32;
#pragma unroll
    for (int g = 0; g < 2; ++g) {
        u32 hw[4], lw[4];
#pragma unroll
        for (int p = 0; p < 4; ++p) {
            float v0 = acc[g * 8 + 2 * p], v1 = acc[g * 8 + 2 * p + 1];
            u16 h0 = f2bf(v0), h1 = f2bf(v1);
            hw[p] = (u32)h0 | ((u32)h1 << 16);
            lw[p] = (u32)f2bf(v0 - bf2f(h0)) | ((u32)f2bf(v1 - bf2f(h1)) << 16);
        }
        *reinterpret_cast<uint4*>(op + g * 16) = make_uint4(hw[0], hw[1], hw[2], hw[3]);
        *reinterpret_cast<uint4*>(op + g * 16 + 8) = make_uint4(lw[0], lw[1], lw[2], lw[3]);
    }
}

// ------ 2-wave direct-fragment MFMA gathered GEMM (no LDS, no barriers) -----
// 128 threads = 2 independent waves; wave w owns rows [blk*64 + w*32, +32).
// Wave tile 32 x (16*FN): one A gather feeds FN col-frags (amortizes the
// per-step fixed cost: 2 idx + 4 A vmem + addr VALU over 6*FN MFMAs).
// FN=2 -> bounds (128,4), VGPR<=128 (measured 56). FN=4 -> bounds (128,2),
// VGPR budget 256 (est ~160, NO spill - R9/R11 lesson).
// x: [row][2*CIN] u16, per 8-k group [h8|l8]. wt: k-group-major (see wsplit).
template<int CIN, int COUT, int FN, int KSPLIT, bool BFOUT>
__global__ __launch_bounds__(128, (FN == 2 ? 4 : 2)) void conv_direct(
    const u16* __restrict__ x, const int* __restrict__ nmap,
    const u16* __restrict__ wt,
    float* __restrict__ outf, u16* __restrict__ o, int N)
{
    constexpr int K = 27 * CIN;
    constexpr int KSTEPS = (K + 31) / 32;
    constexpr int KPER = (KSTEPS + KSPLIT - 1) / KSPLIT;
    static_assert(KPER * KSPLIT >= KSTEPS, "");
    constexpr int WN = 16 * FN;

    const int lane = threadIdx.x & 63;
    const int wv = threadIdx.x >> 6;
    const int fr = lane & 15;
    const int kc = lane >> 4;
    const int row0 = (blockIdx.x * 2 + wv) * 32;
    const int co0 = blockIdx.y * WN;
    const int ks0 = blockIdx.z * KPER;

    float4v acc[2][FN];
#pragma unroll
    for (int i = 0; i < 2; ++i)
#pragma unroll
        for (int j = 0; j < FN; ++j) acc[i][j] = (float4v){0.f, 0.f, 0.f, 0.f};

    int idxq[3][2];
    short8 ah[2][2], al[2][2], bh[2][FN], bl[2][FN];
    const short8 zero8 = (short8){0, 0, 0, 0, 0, 0, 0, 0};

    auto load_idx = [&](int s, int slot) {
        int kk8 = (ks0 + s) * 32 + kc * 8;
        int koff = kk8 / CIN;
#pragma unroll
        for (int i = 0; i < 2; ++i) {
            int r = row0 + i * 16 + fr;
            idxq[slot][i] = (kk8 < K && r < N) ? nmap[(size_t)koff * N + r] : -1;
        }
    };
    auto load_frag = [&](int s, int islot, int p) {
        int kk8 = (ks0 + s) * 32 + kc * 8;
        int cg = (kk8 & (CIN - 1)) >> 3;
#pragma unroll
        for (int i = 0; i < 2; ++i) {
            int idx = idxq[islot][i];
            if (idx >= 0) {
                const u16* base = x + (size_t)idx * (2 * CIN) + cg * 16;
                ah[p][i] = *reinterpret_cast<const short8*>(base);
                al[p][i] = *reinterpret_cast<const short8*>(base + 8);
            } else {
                ah[p][i] = zero8;
                al[p][i] = zero8;
            }
        }
        int g = (ks0 + s) * 4 + kc;
        bool ok = (g * 8) < K;
#pragma unroll
        for (int j = 0; j < FN; ++j) {
            const u16* bp = wt + ((size_t)g * COUT + (co0 + j * 16 + fr)) * 16;
            bh[p][j] = ok ? *reinterpret_cast<const short8*>(bp) : zero8;
            bl[p][j] = ok ? *reinterpret_cast<const short8*>(bp + 8) : zero8;
        }
    };
    auto mm = [&](int p) {
#pragma unroll
        for (int i = 0; i < 2; ++i)
#pragma unroll
            for (int j = 0; j < FN; ++j) {
                acc[i][j] = __builtin_amdgcn_mfma_f32_16x16x32_bf16(ah[p][i], bh[p][j], acc[i][j], 0, 0, 0);
                acc[i][j] = __builtin_amdgcn_mfma_f32_16x16x32_bf16(ah[p][i], bl[p][j], acc[i][j], 0, 0, 0);
                acc[i][j] = __builtin_amdgcn_mfma_f32_16x16x32_bf16(al[p][i], bh[p][j], acc[i][j], 0, 0, 0);
            }
    };

    load_idx(0, 0);
    if (KPER > 1) load_idx(1, 1);
    if (KPER > 2) load_idx(2, 2);
    load_frag(0, 0, 0);
#pragma unroll
    for (int s = 0; s < KPER; ++s) {
        if (s + 3 < KPER) load_idx(s + 3, (s + 3) % 3);
        if (s + 1 < KPER) load_frag(s + 1, (s + 1) % 3, (s + 1) & 1);
        mm(s & 1);
    }

    // D layout: row=(lane>>4)*4+q, col=lane&15 (m89)
    const int orow0 = row0 + (lane >> 4) * 4;
    const int ocol0 = co0 + fr;
#pragma unroll
    for (int i = 0; i < 2; ++i)
#pragma unroll
        for (int j = 0; j < FN; ++j)
#pragma unroll
            for (int q = 0; q < 4; ++q) {
                int r = orow0 + i * 16 + q;
                int c = ocol0 + j * 16;
                if (r < N) {
                    float v = acc[i][j][q];
                    if constexpr (BFOUT) {
                        u16 h = f2bf(v);
                        size_t base = (size_t)r * (2 * COUT) + ((c >> 3) * 16) + (c & 7);
                        o[base] = h;
                        o[base + 8] = f2bf(v - bf2f(h));
                    } else {
                        outf[(size_t)blockIdx.z * N * COUT + (size_t)r * COUT + c] = v;
                    }
                }
            }
}

// ------ deterministic fixed-order K-split reductions ------
__global__ __launch_bounds__(256) void reduce_f32(
    const float* __restrict__ p, float* __restrict__ out, int m4, int S)
{
    int i = blockIdx.x * 256 + threadIdx.x;
    if (i >= m4) return;
    const float4* p4 = reinterpret_cast<const float4*>(p);
    float4 a = p4[i];
    for (int s = 1; s < S; ++s) {
        float4 v = p4[(size_t)s * m4 + i];
        a.x += v.x; a.y += v.y; a.z += v.z; a.w += v.w;
    }
    reinterpret_cast<float4*>(out)[i] = a;
}
template<int C>
__global__ __launch_bounds__(256) void reduce_bf(
    const float* __restrict__ p, u16* __restrict__ o, int m, int S)
{
    int i = blockIdx.x * 256 + threadIdx.x;
    if (i >= m) return;
    float a = p[i];
    for (int s = 1; s < S; ++s) a += p[(size_t)s * m + i];
    int r = i / C, c = i % C;
    u16 h = f2bf(a);
    size_t base = (size_t)r * (2 * C) + ((c >> 3) * 16) + (c & 7);
    o[base] = h;
    o[base + 8] = f2bf(a - bf2f(h));
}

extern "C" void kernel_launch(void* const* d_in, const int* in_sizes, int n_in,
                              void* d_out, int out_size, void* d_ws, size_t ws_size,
                              hipStream_t stream)
{
    const float* feats = (const float*)d_in[0];
    const float* W1 = (const float*)d_in[1];
    const int*   nm1 = (const int*)d_in[2];
    const float* W2 = (const float*)d_in[3];
    const int*   nm2 = (const int*)d_in[4];
    const float* W3 = (const float*)d_in[5];
    const int*   nm3 = (const int*)d_in[6];
    const float* W4 = (const float*)d_in[7];
    const int*   nm4 = (const int*)d_in[8];
    const float* W5 = (const float*)d_in[9];
    const int*   nm5 = (const int*)d_in[10];

    const int M1 = in_sizes[2] / 27;
    const int M2 = in_sizes[4] / 27;
    const int M3 = in_sizes[6] / 27;
    const int M4 = in_sizes[8] / 27;
    const int M5 = in_sizes[10] / 27;

    u16* x1 = (u16*)d_ws;                        // M1 x 32
    u16* x2 = x1 + (size_t)M1 * 32;              // M2 x 64
    u16* x3 = x2 + (size_t)M2 * 64;              // M3 x 128
    u16* x4 = x3 + (size_t)M3 * 128;             // M4 x 256
    u16* wt2 = x4 + (size_t)M4 * 256;            // 2*432*32
    u16* wt3 = wt2 + 2 * 432 * 32;               // 2*864*64
    u16* wt4 = wt3 + 2 * 864 * 64;               // 2*1728*128
    u16* wt5 = wt4 + 2 * 1728 * 128;             // 2*3456*512
    // partials alias dead regions (p4 on x1: dead after L2; p5 on x2: dead after L3)
    float* p4 = (float*)x1;                      // 2 * M4*128 f32
    float* p5 = (float*)x2;                      // 4 * M5*512 f32

    wsplit<<<cdiv(432 * 32, 256), 256, 0, stream>>>(W2, wt2, 432, 32);
    wsplit<<<cdiv(864 * 64, 256), 256, 0, stream>>>(W3, wt3, 864, 64);
    wsplit<<<cdiv(1728 * 128, 256), 256, 0, stream>>>(W4, wt4, 1728, 128);
    wsplit<<<cdiv(3456 * 512, 256), 256, 0, stream>>>(W5, wt5, 3456, 512);

    conv_l1<<<cdiv(M1, 256), 256, 0, stream>>>(feats, nm1, W1, x1, M1);

    // L2: 16 -> 32, FN=2 (COUT=32 caps tile), KPER=14
    conv_direct<16, 32, 2, 1, true>
        <<<dim3(cdiv(M2, 64), 1, 1), 128, 0, stream>>>(
            x1, nm2, wt2, nullptr, x2, M2);
    // L3: 32 -> 64, FN=4 (wave tile 32x64), KPER=27
    conv_direct<32, 64, 4, 1, true>
        <<<dim3(cdiv(M3, 64), 1, 1), 128, 0, stream>>>(
            x2, nm3, wt3, nullptr, x3, M3);
    // L4: 64 -> 128, FN=4, K-split 2 (KPER=27)
    conv_direct<64, 128, 4, 2, false>
        <<<dim3(cdiv(M4, 64), 2, 2), 128, 0, stream>>>(
            x3, nm4, wt4, p4, nullptr, M4);
    reduce_bf<128><<<cdiv(M4 * 128, 256), 256, 0, stream>>>(p4, x4, M4 * 128, 2);
    // L5: 128 -> 512, FN=4, K-split 4 (KPER=27)
    conv_direct<128, 512, 4, 4, false>
        <<<dim3(cdiv(M5, 64), 8, 4), 128, 0, stream>>>(
            x4, nm5, wt5, p5, nullptr, M5);
    reduce_f32<<<cdiv(M5 * 512 / 4, 256), 256, 0, stream>>>(p5, (float*)d_out, M5 * 512 / 4, 4);
}

// Round 14
// 127.355 us; speedup vs baseline: 3.4456x; 1.1807x over previous
//
#include <hip/hip_runtime.h>

typedef unsigned short u16;
typedef unsigned int u32;
typedef __attribute__((ext_vector_type(8))) short short8;
typedef __attribute__((ext_vector_type(4))) float float4v;

static inline int cdiv(int a, int b) { return (a + b - 1) / b; }

__device__ __forceinline__ u16 f2bf(float f) {
    u32 u = __float_as_uint(f);
    u = (u + 0x7fffu + ((u >> 16) & 1u)) >> 16;
    return (u16)u;
}
__device__ __forceinline__ float bf2f(u16 s) {
    return __uint_as_float(((u32)s) << 16);
}

// W ([K][COUT] fp32) -> bf16 hi/lo, k-group-major: wt[(g*COUT + co)*16 + (k&7)]
// h at +0..7, l at +8..15  (g = k>>3). B-frag loads coalesce across co lanes.
// W keeps hi/lo 2-term precision; activations are plain bf16 (2-term scheme).
__global__ __launch_bounds__(256) void wsplit(
    const float* __restrict__ W, u16* __restrict__ wt, int K, int COUT)
{
    int e = blockIdx.x * 256 + threadIdx.x;
    if (e >= K * COUT) return;
    int kk = e / COUT, co = e % COUT;
    float w = W[e];
    u16 h = f2bf(w);
    u16 l = f2bf(w - bf2f(h));
    size_t base = ((size_t)(kk >> 3) * COUT + co) * 16 + (kk & 7);
    wt[base] = h;
    wt[base + 8] = l;
}

// ------ Layer 1: C_in=1 -> 16. ONE thread per row, unroll 3; bf16 out ------
__global__ __launch_bounds__(256) void conv_l1(
    const float* __restrict__ feats, const int* __restrict__ nmap,
    const float* __restrict__ W, u16* __restrict__ o, int N)
{
    __shared__ float4 w4[27 * 4];
    for (int i = threadIdx.x; i < 27 * 4; i += 256)
        w4[i] = reinterpret_cast<const float4*>(W)[i];
    __syncthreads();

    const int row = blockIdx.x * 256 + threadIdx.x;
    if (row >= N) return;

    float acc[16];
#pragma unroll
    for (int j = 0; j < 16; ++j) acc[j] = 0.f;

#pragma unroll 3
    for (int k = 0; k < 27; ++k) {
        int idx = nmap[(size_t)k * N + row];
        float v = (idx >= 0) ? feats[idx] : 0.f;
#pragma unroll
        for (int cq = 0; cq < 4; ++cq) {
            float4 w = w4[k * 4 + cq];   // uniform address -> LDS broadcast
            acc[cq * 4 + 0] = fmaf(v, w.x, acc[cq * 4 + 0]);
            acc[cq * 4 + 1] = fmaf(v, w.y, acc[cq * 4 + 1]);
            acc[cq * 4 + 2] = fmaf(v, w.z, acc[cq * 4 + 2]);
            acc[cq * 4 + 3] = fmaf(v, w.w, acc[cq * 4 + 3]);
        }
    }

    // plain bf16 row (16 u16 = 32 B): 2 x 16B coalesced stores
    u16* op = o + (size_t)row * 16;
    u32 w8[8];
#pragma unroll
    for (int p = 0; p < 8; ++p)
        w8[p] = (u32)f2bf(acc[2 * p]) | ((u32)f2bf(acc[2 * p + 1]) << 16);
    *reinterpret_cast<uint4*>(op) = make_uint4(w8[0], w8[1], w8[2], w8[3]);
    *reinterpret_cast<uint4*>(op + 8) = make_uint4(w8[4], w8[5], w8[6], w8[7]);
}

// ------ 2-wave direct-fragment MFMA gathered GEMM (no LDS, no barriers) -----
// 2-TERM scheme: acc += xh*Wh + xh*Wl (activations bf16, weights hi/lo).
// 128 threads = 2 independent waves; wave w owns rows [blk*64 + w*32, +32).
// Wave tile 32 x (16*FN). Per K-step: 2 idx + 2 A + 2*FN B vmem, 4*FN MFMA.
// x: [row][CIN] u16 bf16. wt: k-group-major (see wsplit).
// FN=2 -> bounds (128,4) cap 128 VGPR (est ~45). FN=4 -> (128,3) cap ~170
// (est ~105) - NO spill (R9/R11 lesson; tripwire: WRITE_SIZE).
template<int CIN, int COUT, int FN, int KSPLIT, bool BFOUT>
__global__ __launch_bounds__(128, (FN == 2 ? 4 : 3)) void conv_direct(
    const u16* __restrict__ x, const int* __restrict__ nmap,
    const u16* __restrict__ wt,
    float* __restrict__ outf, u16* __restrict__ o, int N)
{
    constexpr int K = 27 * CIN;
    constexpr int KSTEPS = (K + 31) / 32;
    constexpr int KPER = (KSTEPS + KSPLIT - 1) / KSPLIT;
    static_assert(KPER * KSPLIT >= KSTEPS, "");
    constexpr int WN = 16 * FN;

    const int lane = threadIdx.x & 63;
    const int wv = threadIdx.x >> 6;
    const int fr = lane & 15;
    const int kc = lane >> 4;
    const int row0 = (blockIdx.x * 2 + wv) * 32;
    const int co0 = blockIdx.y * WN;
    const int ks0 = blockIdx.z * KPER;

    float4v acc[2][FN];
#pragma unroll
    for (int i = 0; i < 2; ++i)
#pragma unroll
        for (int j = 0; j < FN; ++j) acc[i][j] = (float4v){0.f, 0.f, 0.f, 0.f};

    int idxq[3][2];
    short8 ah[2][2], bh[2][FN], bl[2][FN];
    const short8 zero8 = (short8){0, 0, 0, 0, 0, 0, 0, 0};

    auto load_idx = [&](int s, int slot) {
        int kk8 = (ks0 + s) * 32 + kc * 8;
        int koff = kk8 / CIN;
#pragma unroll
        for (int i = 0; i < 2; ++i) {
            int r = row0 + i * 16 + fr;
            idxq[slot][i] = (kk8 < K && r < N) ? nmap[(size_t)koff * N + r] : -1;
        }
    };
    auto load_frag = [&](int s, int islot, int p) {
        int kk8 = (ks0 + s) * 32 + kc * 8;
        int cg8 = kk8 & (CIN - 1);
#pragma unroll
        for (int i = 0; i < 2; ++i) {
            int idx = idxq[islot][i];
            ah[p][i] = (idx >= 0)
                ? *reinterpret_cast<const short8*>(x + (size_t)idx * CIN + cg8)
                : zero8;
        }
        int g = (ks0 + s) * 4 + kc;
        bool ok = (g * 8) < K;
#pragma unroll
        for (int j = 0; j < FN; ++j) {
            const u16* bp = wt + ((size_t)g * COUT + (co0 + j * 16 + fr)) * 16;
            bh[p][j] = ok ? *reinterpret_cast<const short8*>(bp) : zero8;
            bl[p][j] = ok ? *reinterpret_cast<const short8*>(bp + 8) : zero8;
        }
    };
    auto mm = [&](int p) {
#pragma unroll
        for (int i = 0; i < 2; ++i)
#pragma unroll
            for (int j = 0; j < FN; ++j) {
                acc[i][j] = __builtin_amdgcn_mfma_f32_16x16x32_bf16(ah[p][i], bh[p][j], acc[i][j], 0, 0, 0);
                acc[i][j] = __builtin_amdgcn_mfma_f32_16x16x32_bf16(ah[p][i], bl[p][j], acc[i][j], 0, 0, 0);
            }
    };

    load_idx(0, 0);
    if (KPER > 1) load_idx(1, 1);
    if (KPER > 2) load_idx(2, 2);
    load_frag(0, 0, 0);
#pragma unroll
    for (int s = 0; s < KPER; ++s) {
        if (s + 3 < KPER) load_idx(s + 3, (s + 3) % 3);
        if (s + 1 < KPER) load_frag(s + 1, (s + 1) % 3, (s + 1) & 1);
        mm(s & 1);
    }

    // D layout: row=(lane>>4)*4+q, col=lane&15 (m89)
    const int orow0 = row0 + (lane >> 4) * 4;
    const int ocol0 = co0 + fr;
#pragma unroll
    for (int i = 0; i < 2; ++i)
#pragma unroll
        for (int j = 0; j < FN; ++j)
#pragma unroll
            for (int q = 0; q < 4; ++q) {
                int r = orow0 + i * 16 + q;
                int c = ocol0 + j * 16;
                if (r < N) {
                    float v = acc[i][j][q];
                    if constexpr (BFOUT) {
                        o[(size_t)r * COUT + c] = f2bf(v);
                    } else {
                        outf[(size_t)blockIdx.z * N * COUT + (size_t)r * COUT + c] = v;
                    }
                }
            }
}

// ------ deterministic fixed-order K-split reductions ------
__global__ __launch_bounds__(256) void reduce_f32(
    const float* __restrict__ p, float* __restrict__ out, int m4, int S)
{
    int i = blockIdx.x * 256 + threadIdx.x;
    if (i >= m4) return;
    const float4* p4 = reinterpret_cast<const float4*>(p);
    float4 a = p4[i];
    for (int s = 1; s < S; ++s) {
        float4 v = p4[(size_t)s * m4 + i];
        a.x += v.x; a.y += v.y; a.z += v.z; a.w += v.w;
    }
    reinterpret_cast<float4*>(out)[i] = a;
}
__global__ __launch_bounds__(256) void reduce_bf(
    const float* __restrict__ p, u16* __restrict__ o, int m, int S)
{
    int i = blockIdx.x * 256 + threadIdx.x;
    if (i >= m) return;
    float a = p[i];
    for (int s = 1; s < S; ++s) a += p[(size_t)s * m + i];
    o[i] = f2bf(a);
}

extern "C" void kernel_launch(void* const* d_in, const int* in_sizes, int n_in,
                              void* d_out, int out_size, void* d_ws, size_t ws_size,
                              hipStream_t stream)
{
    const float* feats = (const float*)d_in[0];
    const float* W1 = (const float*)d_in[1];
    const int*   nm1 = (const int*)d_in[2];
    const float* W2 = (const float*)d_in[3];
    const int*   nm2 = (const int*)d_in[4];
    const float* W3 = (const float*)d_in[5];
    const int*   nm3 = (const int*)d_in[6];
    const float* W4 = (const float*)d_in[7];
    const int*   nm4 = (const int*)d_in[8];
    const float* W5 = (const float*)d_in[9];
    const int*   nm5 = (const int*)d_in[10];

    const int M1 = in_sizes[2] / 27;
    const int M2 = in_sizes[4] / 27;
    const int M3 = in_sizes[6] / 27;
    const int M4 = in_sizes[8] / 27;
    const int M5 = in_sizes[10] / 27;

    u16* x1 = (u16*)d_ws;                        // M1 x 16
    u16* x2 = x1 + (size_t)M1 * 16;              // M2 x 32
    u16* x3 = x2 + (size_t)M2 * 32;              // M3 x 64
    u16* x4 = x3 + (size_t)M3 * 64;              // M4 x 128
    u16* wt2 = x4 + (size_t)M4 * 128;            // 2*432*32
    u16* wt3 = wt2 + 2 * 432 * 32;               // 2*864*64
    u16* wt4 = wt3 + 2 * 864 * 64;               // 2*1728*128
    u16* wt5 = wt4 + 2 * 1728 * 128;             // 2*3456*512
    // partials alias dead regions (p4 on x1: dead after L2 [4.2MB<=11.8MB];
    // p5 on x2: dead after L3 [4.2MB<=11.7MB])
    float* p4 = (float*)x1;                      // 2 * M4*128 f32
    float* p5 = (float*)x2;                      // 4 * M5*512 f32

    wsplit<<<cdiv(432 * 32, 256), 256, 0, stream>>>(W2, wt2, 432, 32);
    wsplit<<<cdiv(864 * 64, 256), 256, 0, stream>>>(W3, wt3, 864, 64);
    wsplit<<<cdiv(1728 * 128, 256), 256, 0, stream>>>(W4, wt4, 1728, 128);
    wsplit<<<cdiv(3456 * 512, 256), 256, 0, stream>>>(W5, wt5, 3456, 512);

    conv_l1<<<cdiv(M1, 256), 256, 0, stream>>>(feats, nm1, W1, x1, M1);

    // L2: 16 -> 32, FN=2 (COUT=32 caps tile), KPER=14
    conv_direct<16, 32, 2, 1, true>
        <<<dim3(cdiv(M2, 64), 1, 1), 128, 0, stream>>>(
            x1, nm2, wt2, nullptr, x2, M2);
    // L3: 32 -> 64, FN=4 (wave tile 32x64), KPER=27
    conv_direct<32, 64, 4, 1, true>
        <<<dim3(cdiv(M3, 64), 1, 1), 128, 0, stream>>>(
            x2, nm3, wt3, nullptr, x3, M3);
    // L4: 64 -> 128, FN=4, K-split 2 (KPER=27)
    conv_direct<64, 128, 4, 2, false>
        <<<dim3(cdiv(M4, 64), 2, 2), 128, 0, stream>>>(
            x3, nm4, wt4, p4, nullptr, M4);
    reduce_bf<<<cdiv(M4 * 128, 256), 256, 0, stream>>>(p4, x4, M4 * 128, 2);
    // L5: 128 -> 512, FN=4, K-split 4 (KPER=27)
    conv_direct<128, 512, 4, 4, false>
        <<<dim3(cdiv(M5, 64), 8, 4), 128, 0, stream>>>(
            x4, nm5, wt5, p5, nullptr, M5);
    reduce_f32<<<cdiv(M5 * 512 / 4, 256), 256, 0, stream>>>(p5, (float*)d_out, M5 * 512 / 4, 4);
}

// Round 15
// 117.239 us; speedup vs baseline: 3.7429x; 1.0863x over previous
//
#include <hip/hip_runtime.h>

typedef unsigned short u16;
typedef unsigned int u32;
typedef __attribute__((ext_vector_type(8))) short short8;
typedef __attribute__((ext_vector_type(4))) float float4v;

static inline int cdiv(int a, int b) { return (a + b - 1) / b; }

__device__ __forceinline__ u16 f2bf(float f) {
    u32 u = __float_as_uint(f);
    u = (u + 0x7fffu + ((u >> 16) & 1u)) >> 16;
    return (u16)u;
}
__device__ __forceinline__ float bf2f(u16 s) {
    return __uint_as_float(((u32)s) << 16);
}

// W ([K][COUT] fp32) -> bf16 hi/lo, k-group-major: wt[(g*COUT + co)*16 + (k&7)]
// h at +0..7, l at +8..15  (g = k>>3). B-frag loads coalesce across co lanes.
__global__ __launch_bounds__(256) void wsplit(
    const float* __restrict__ W, u16* __restrict__ wt, int K, int COUT)
{
    int e = blockIdx.x * 256 + threadIdx.x;
    if (e >= K * COUT) return;
    int kk = e / COUT, co = e % COUT;
    float w = W[e];
    u16 h = f2bf(w);
    u16 l = f2bf(w - bf2f(h));
    size_t base = ((size_t)(kk >> 3) * COUT + co) * 16 + (kk & 7);
    wt[base] = h;
    wt[base + 8] = l;
}

// ------ Layer 1: C_in=1 -> 16. ONE thread per row, unroll 3; bf16 out ------
__global__ __launch_bounds__(256) void conv_l1(
    const float* __restrict__ feats, const int* __restrict__ nmap,
    const float* __restrict__ W, u16* __restrict__ o, int N)
{
    __shared__ float4 w4[27 * 4];
    for (int i = threadIdx.x; i < 27 * 4; i += 256)
        w4[i] = reinterpret_cast<const float4*>(W)[i];
    __syncthreads();

    const int row = blockIdx.x * 256 + threadIdx.x;
    if (row >= N) return;

    float acc[16];
#pragma unroll
    for (int j = 0; j < 16; ++j) acc[j] = 0.f;

#pragma unroll 3
    for (int k = 0; k < 27; ++k) {
        int idx = nmap[(size_t)k * N + row];
        float v = (idx >= 0) ? feats[idx] : 0.f;
#pragma unroll
        for (int cq = 0; cq < 4; ++cq) {
            float4 w = w4[k * 4 + cq];   // uniform address -> LDS broadcast
            acc[cq * 4 + 0] = fmaf(v, w.x, acc[cq * 4 + 0]);
            acc[cq * 4 + 1] = fmaf(v, w.y, acc[cq * 4 + 1]);
            acc[cq * 4 + 2] = fmaf(v, w.z, acc[cq * 4 + 2]);
            acc[cq * 4 + 3] = fmaf(v, w.w, acc[cq * 4 + 3]);
        }
    }

    // plain bf16 row (16 u16 = 32 B): 2 x 16B coalesced stores
    u16* op = o + (size_t)row * 16;
    u32 w8[8];
#pragma unroll
    for (int p = 0; p < 8; ++p)
        w8[p] = (u32)f2bf(acc[2 * p]) | ((u32)f2bf(acc[2 * p + 1]) << 16);
    *reinterpret_cast<uint4*>(op) = make_uint4(w8[0], w8[1], w8[2], w8[3]);
    *reinterpret_cast<uint4*>(op + 8) = make_uint4(w8[4], w8[5], w8[6], w8[7]);
}

// ------ 2-wave direct-fragment MFMA gathered GEMM (no LDS, no barriers) -----
// 2-TERM scheme: acc += xh*Wh + xh*Wl (activations bf16, weights hi/lo).
// A-frag ring DEPTH 3 (gather issued 2 K-steps ahead), idx ring depth 4,
// B ring depth 2 (W is cache-hot). All ring indices compile-time (full unroll).
// VGPR: FN=2 ~100 under (128,4) cap 128; FN=4 ~155 under (128,2) cap 256
// (R9/R11 lesson: NEVER overrun the cap; tripwire = WRITE_SIZE).
template<int CIN, int COUT, int FN, int KSPLIT, bool BFOUT>
__global__ __launch_bounds__(128, (FN == 2 ? 4 : 2)) void conv_direct(
    const u16* __restrict__ x, const int* __restrict__ nmap,
    const u16* __restrict__ wt,
    float* __restrict__ outf, u16* __restrict__ o, int N)
{
    constexpr int K = 27 * CIN;
    constexpr int KSTEPS = (K + 31) / 32;
    constexpr int KPER = (KSTEPS + KSPLIT - 1) / KSPLIT;
    static_assert(KPER * KSPLIT >= KSTEPS, "");
    constexpr int WN = 16 * FN;

    const int lane = threadIdx.x & 63;
    const int wv = threadIdx.x >> 6;
    const int fr = lane & 15;
    const int kc = lane >> 4;
    const int row0 = (blockIdx.x * 2 + wv) * 32;
    const int co0 = blockIdx.y * WN;
    const int ks0 = blockIdx.z * KPER;

    float4v acc[2][FN];
#pragma unroll
    for (int i = 0; i < 2; ++i)
#pragma unroll
        for (int j = 0; j < FN; ++j) acc[i][j] = (float4v){0.f, 0.f, 0.f, 0.f};

    int idxq[4][2];
    short8 ah[3][2], bh[2][FN], bl[2][FN];
    const short8 zero8 = (short8){0, 0, 0, 0, 0, 0, 0, 0};

    auto load_idx = [&](int s, int slot) {
        int kk8 = (ks0 + s) * 32 + kc * 8;
        int koff = kk8 / CIN;
#pragma unroll
        for (int i = 0; i < 2; ++i) {
            int r = row0 + i * 16 + fr;
            idxq[slot][i] = (kk8 < K && r < N) ? nmap[(size_t)koff * N + r] : -1;
        }
    };
    auto load_fragA = [&](int s, int islot, int p) {
        int kk8 = (ks0 + s) * 32 + kc * 8;
        int cg8 = kk8 & (CIN - 1);
#pragma unroll
        for (int i = 0; i < 2; ++i) {
            int idx = idxq[islot][i];
            ah[p][i] = (idx >= 0)
                ? *reinterpret_cast<const short8*>(x + (size_t)idx * CIN + cg8)
                : zero8;
        }
    };
    auto load_fragB = [&](int s, int p) {
        int g = (ks0 + s) * 4 + kc;
        bool ok = (g * 8) < K;
#pragma unroll
        for (int j = 0; j < FN; ++j) {
            const u16* bp = wt + ((size_t)g * COUT + (co0 + j * 16 + fr)) * 16;
            bh[p][j] = ok ? *reinterpret_cast<const short8*>(bp) : zero8;
            bl[p][j] = ok ? *reinterpret_cast<const short8*>(bp + 8) : zero8;
        }
    };
    auto mm = [&](int pa, int pb) {
#pragma unroll
        for (int i = 0; i < 2; ++i)
#pragma unroll
            for (int j = 0; j < FN; ++j) {
                acc[i][j] = __builtin_amdgcn_mfma_f32_16x16x32_bf16(ah[pa][i], bh[pb][j], acc[i][j], 0, 0, 0);
                acc[i][j] = __builtin_amdgcn_mfma_f32_16x16x32_bf16(ah[pa][i], bl[pb][j], acc[i][j], 0, 0, 0);
            }
    };

    // prologue: idx 0..3, A 0..1, B 0
    load_idx(0, 0);
    if (KPER > 1) load_idx(1, 1);
    if (KPER > 2) load_idx(2, 2);
    if (KPER > 3) load_idx(3, 3);
    load_fragA(0, 0, 0);
    if (KPER > 1) load_fragA(1, 1, 1);
    load_fragB(0, 0);

#pragma unroll
    for (int s = 0; s < KPER; ++s) {
        if (s + 2 < KPER) load_fragA(s + 2, (s + 2) & 3, (s + 2) % 3);
        if (s + 4 < KPER) load_idx(s + 4, (s + 4) & 3);
        if (s + 1 < KPER) load_fragB(s + 1, (s + 1) & 1);
        mm(s % 3, s & 1);
    }

    // D layout: row=(lane>>4)*4+q, col=lane&15 (m89)
    const int orow0 = row0 + (lane >> 4) * 4;
    const int ocol0 = co0 + fr;
#pragma unroll
    for (int i = 0; i < 2; ++i)
#pragma unroll
        for (int j = 0; j < FN; ++j)
#pragma unroll
            for (int q = 0; q < 4; ++q) {
                int r = orow0 + i * 16 + q;
                int c = ocol0 + j * 16;
                if (r < N) {
                    float v = acc[i][j][q];
                    if constexpr (BFOUT) {
                        o[(size_t)r * COUT + c] = f2bf(v);
                    } else {
                        outf[(size_t)blockIdx.z * N * COUT + (size_t)r * COUT + c] = v;
                    }
                }
            }
}

// ------ deterministic fixed-order K-split reductions ------
__global__ __launch_bounds__(256) void reduce_f32(
    const float* __restrict__ p, float* __restrict__ out, int m4, int S)
{
    int i = blockIdx.x * 256 + threadIdx.x;
    if (i >= m4) return;
    const float4* p4 = reinterpret_cast<const float4*>(p);
    float4 a = p4[i];
    for (int s = 1; s < S; ++s) {
        float4 v = p4[(size_t)s * m4 + i];
        a.x += v.x; a.y += v.y; a.z += v.z; a.w += v.w;
    }
    reinterpret_cast<float4*>(out)[i] = a;
}
__global__ __launch_bounds__(256) void reduce_bf(
    const float* __restrict__ p, u16* __restrict__ o, int m, int S)
{
    int i = blockIdx.x * 256 + threadIdx.x;
    if (i >= m) return;
    float a = p[i];
    for (int s = 1; s < S; ++s) a += p[(size_t)s * m + i];
    o[i] = f2bf(a);
}

extern "C" void kernel_launch(void* const* d_in, const int* in_sizes, int n_in,
                              void* d_out, int out_size, void* d_ws, size_t ws_size,
                              hipStream_t stream)
{
    const float* feats = (const float*)d_in[0];
    const float* W1 = (const float*)d_in[1];
    const int*   nm1 = (const int*)d_in[2];
    const float* W2 = (const float*)d_in[3];
    const int*   nm2 = (const int*)d_in[4];
    const float* W3 = (const float*)d_in[5];
    const int*   nm3 = (const int*)d_in[6];
    const float* W4 = (const float*)d_in[7];
    const int*   nm4 = (const int*)d_in[8];
    const float* W5 = (const float*)d_in[9];
    const int*   nm5 = (const int*)d_in[10];

    const int M1 = in_sizes[2] / 27;
    const int M2 = in_sizes[4] / 27;
    const int M3 = in_sizes[6] / 27;
    const int M4 = in_sizes[8] / 27;
    const int M5 = in_sizes[10] / 27;

    u16* x1 = (u16*)d_ws;                        // M1 x 16
    u16* x2 = x1 + (size_t)M1 * 16;              // M2 x 32
    u16* x3 = x2 + (size_t)M2 * 32;              // M3 x 64
    u16* x4 = x3 + (size_t)M3 * 64;              // M4 x 128
    u16* wt2 = x4 + (size_t)M4 * 128;            // 2*432*32
    u16* wt3 = wt2 + 2 * 432 * 32;               // 2*864*64
    u16* wt4 = wt3 + 2 * 864 * 64;               // 2*1728*128
    u16* wt5 = wt4 + 2 * 1728 * 128;             // 2*3456*512
    // partials alias dead regions:
    // p4 on x1 (dead after L2): 4*M4*128*4B ~= M4*2KB <= M1*32B  ✓
    // p5 on x2 (dead after L3): 8*M5*512*4B ~= M5*16KB <= M2*64B ✓
    float* p4 = (float*)x1;
    float* p5 = (float*)x2;

    wsplit<<<cdiv(432 * 32, 256), 256, 0, stream>>>(W2, wt2, 432, 32);
    wsplit<<<cdiv(864 * 64, 256), 256, 0, stream>>>(W3, wt3, 864, 64);
    wsplit<<<cdiv(1728 * 128, 256), 256, 0, stream>>>(W4, wt4, 1728, 128);
    wsplit<<<cdiv(3456 * 512, 256), 256, 0, stream>>>(W5, wt5, 3456, 512);

    conv_l1<<<cdiv(M1, 256), 256, 0, stream>>>(feats, nm1, W1, x1, M1);

    // L2: 16 -> 32, FN=2 (COUT=32 caps tile), KPER=14
    conv_direct<16, 32, 2, 1, true>
        <<<dim3(cdiv(M2, 64), 1, 1), 128, 0, stream>>>(
            x1, nm2, wt2, nullptr, x2, M2);
    // L3: 32 -> 64, FN=4 (wave tile 32x64), KPER=27
    conv_direct<32, 64, 4, 1, true>
        <<<dim3(cdiv(M3, 64), 1, 1), 128, 0, stream>>>(
            x2, nm3, wt3, nullptr, x3, M3);
    // L4: 64 -> 128, FN=4, K-split 4 (KPER=14)
    conv_direct<64, 128, 4, 4, false>
        <<<dim3(cdiv(M4, 64), 2, 4), 128, 0, stream>>>(
            x3, nm4, wt4, p4, nullptr, M4);
    reduce_bf<<<cdiv(M4 * 128, 256), 256, 0, stream>>>(p4, x4, M4 * 128, 4);
    // L5: 128 -> 512, FN=4, K-split 8 (KPER=14)
    conv_direct<128, 512, 4, 8, false>
        <<<dim3(cdiv(M5, 64), 8, 8), 128, 0, stream>>>(
            x4, nm5, wt5, p5, nullptr, M5);
    reduce_f32<<<cdiv(M5 * 512 / 4, 256), 256, 0, stream>>>(p5, (float*)d_out, M5 * 512 / 4, 8);
}

// Round 16
// 88.320 us; speedup vs baseline: 4.9685x; 1.3274x over previous
//
#include <hip/hip_runtime.h>

typedef unsigned short u16;
typedef unsigned int u32;
typedef __attribute__((ext_vector_type(8))) short short8;
typedef __attribute__((ext_vector_type(4))) float float4v;

static inline int cdiv(int a, int b) { return (a + b - 1) / b; }

__device__ __forceinline__ u16 f2bf(float f) {
    u32 u = __float_as_uint(f);
    u = (u + 0x7fffu + ((u >> 16) & 1u)) >> 16;
    return (u16)u;
}
__device__ __forceinline__ float bf2f(u16 s) {
    return __uint_as_float(((u32)s) << 16);
}

// ---- fused weight cast: W ([K][COUT] fp32) -> bf16, k-group-major:
// wt[((k>>3)*COUT + co)*8 + (k&7)].  All 4 layer weights in one launch.
__device__ __forceinline__ void wcast_one(
    const float* __restrict__ W, u16* __restrict__ wt, int COUT, int e)
{
    int kk = e / COUT, co = e % COUT;
    wt[((size_t)(kk >> 3) * COUT + co) * 8 + (kk & 7)] = f2bf(W[e]);
}
__global__ __launch_bounds__(256) void wcast4(
    const float* __restrict__ W2, const float* __restrict__ W3,
    const float* __restrict__ W4, const float* __restrict__ W5,
    u16* __restrict__ t2, u16* __restrict__ t3,
    u16* __restrict__ t4, u16* __restrict__ t5)
{
    constexpr int n2 = 432 * 32, n3 = 864 * 64, n4 = 1728 * 128, n5 = 3456 * 512;
    int e = blockIdx.x * 256 + threadIdx.x;
    if (e < n2) { wcast_one(W2, t2, 32, e); return; }
    e -= n2;
    if (e < n3) { wcast_one(W3, t3, 64, e); return; }
    e -= n3;
    if (e < n4) { wcast_one(W4, t4, 128, e); return; }
    e -= n4;
    if (e < n5) { wcast_one(W5, t5, 512, e); }
}

// ------ Layer 1: C_in=1 -> 16. ONE thread per row, unroll 3; bf16 out ------
__global__ __launch_bounds__(256) void conv_l1(
    const float* __restrict__ feats, const int* __restrict__ nmap,
    const float* __restrict__ W, u16* __restrict__ o, int N)
{
    __shared__ float4 w4[27 * 4];
    for (int i = threadIdx.x; i < 27 * 4; i += 256)
        w4[i] = reinterpret_cast<const float4*>(W)[i];
    __syncthreads();

    const int row = blockIdx.x * 256 + threadIdx.x;
    if (row >= N) return;

    float acc[16];
#pragma unroll
    for (int j = 0; j < 16; ++j) acc[j] = 0.f;

#pragma unroll 3
    for (int k = 0; k < 27; ++k) {
        int idx = nmap[(size_t)k * N + row];
        float v = (idx >= 0) ? feats[idx] : 0.f;
#pragma unroll
        for (int cq = 0; cq < 4; ++cq) {
            float4 w = w4[k * 4 + cq];   // uniform address -> LDS broadcast
            acc[cq * 4 + 0] = fmaf(v, w.x, acc[cq * 4 + 0]);
            acc[cq * 4 + 1] = fmaf(v, w.y, acc[cq * 4 + 1]);
            acc[cq * 4 + 2] = fmaf(v, w.z, acc[cq * 4 + 2]);
            acc[cq * 4 + 3] = fmaf(v, w.w, acc[cq * 4 + 3]);
        }
    }

    // plain bf16 row (16 u16 = 32 B): 2 x 16B coalesced stores
    u16* op = o + (size_t)row * 16;
    u32 w8[8];
#pragma unroll
    for (int p = 0; p < 8; ++p)
        w8[p] = (u32)f2bf(acc[2 * p]) | ((u32)f2bf(acc[2 * p + 1]) << 16);
    *reinterpret_cast<uint4*>(op) = make_uint4(w8[0], w8[1], w8[2], w8[3]);
    *reinterpret_cast<uint4*>(op + 8) = make_uint4(w8[4], w8[5], w8[6], w8[7]);
}

// ------ 2-wave direct-fragment MFMA gathered GEMM (no LDS, no barriers) -----
// 1-TERM scheme: acc += x_bf16 * W_bf16 (absmax budget verified R14: 2-term
// gave 1.95e-3 vs 9.26e-3 threshold; weight-quant adds ~same magnitude).
// A-frag ring DEPTH 3 (gather issued 2 K-steps ahead), idx ring depth 4,
// B ring depth 2 (cache-hot). All ring indices compile-time (full unroll).
// VGPR: FN=2 ~90 under (128,4) cap 128; FN=4 ~120 under (128,3) cap ~168
// (R9/R11 lesson: NEVER overrun the cap; tripwire = WRITE_SIZE).
template<int CIN, int COUT, int FN, int KSPLIT, bool BFOUT>
__global__ __launch_bounds__(128, (FN == 2 ? 4 : 3)) void conv_direct(
    const u16* __restrict__ x, const int* __restrict__ nmap,
    const u16* __restrict__ wt,
    float* __restrict__ outf, u16* __restrict__ o, int N)
{
    constexpr int K = 27 * CIN;
    constexpr int KSTEPS = (K + 31) / 32;
    constexpr int KPER = (KSTEPS + KSPLIT - 1) / KSPLIT;
    static_assert(KPER * KSPLIT >= KSTEPS, "");
    constexpr int WN = 16 * FN;

    const int lane = threadIdx.x & 63;
    const int wv = threadIdx.x >> 6;
    const int fr = lane & 15;
    const int kc = lane >> 4;
    const int row0 = (blockIdx.x * 2 + wv) * 32;
    const int co0 = blockIdx.y * WN;
    const int ks0 = blockIdx.z * KPER;

    float4v acc[2][FN];
#pragma unroll
    for (int i = 0; i < 2; ++i)
#pragma unroll
        for (int j = 0; j < FN; ++j) acc[i][j] = (float4v){0.f, 0.f, 0.f, 0.f};

    int idxq[4][2];
    short8 ah[3][2], bh[2][FN];
    const short8 zero8 = (short8){0, 0, 0, 0, 0, 0, 0, 0};

    auto load_idx = [&](int s, int slot) {
        int kk8 = (ks0 + s) * 32 + kc * 8;
        int koff = kk8 / CIN;
#pragma unroll
        for (int i = 0; i < 2; ++i) {
            int r = row0 + i * 16 + fr;
            idxq[slot][i] = (kk8 < K && r < N) ? nmap[(size_t)koff * N + r] : -1;
        }
    };
    auto load_fragA = [&](int s, int islot, int p) {
        int kk8 = (ks0 + s) * 32 + kc * 8;
        int cg8 = kk8 & (CIN - 1);
#pragma unroll
        for (int i = 0; i < 2; ++i) {
            int idx = idxq[islot][i];
            ah[p][i] = (idx >= 0)
                ? *reinterpret_cast<const short8*>(x + (size_t)idx * CIN + cg8)
                : zero8;
        }
    };
    auto load_fragB = [&](int s, int p) {
        int g = (ks0 + s) * 4 + kc;
        bool ok = (g * 8) < K;
#pragma unroll
        for (int j = 0; j < FN; ++j) {
            const u16* bp = wt + ((size_t)g * COUT + (co0 + j * 16 + fr)) * 8;
            bh[p][j] = ok ? *reinterpret_cast<const short8*>(bp) : zero8;
        }
    };
    auto mm = [&](int pa, int pb) {
#pragma unroll
        for (int i = 0; i < 2; ++i)
#pragma unroll
            for (int j = 0; j < FN; ++j)
                acc[i][j] = __builtin_amdgcn_mfma_f32_16x16x32_bf16(ah[pa][i], bh[pb][j], acc[i][j], 0, 0, 0);
    };

    // prologue: idx 0..3, A 0..1, B 0
    load_idx(0, 0);
    if (KPER > 1) load_idx(1, 1);
    if (KPER > 2) load_idx(2, 2);
    if (KPER > 3) load_idx(3, 3);
    load_fragA(0, 0, 0);
    if (KPER > 1) load_fragA(1, 1, 1);
    load_fragB(0, 0);

#pragma unroll
    for (int s = 0; s < KPER; ++s) {
        if (s + 2 < KPER) load_fragA(s + 2, (s + 2) & 3, (s + 2) % 3);
        if (s + 4 < KPER) load_idx(s + 4, (s + 4) & 3);
        if (s + 1 < KPER) load_fragB(s + 1, (s + 1) & 1);
        mm(s % 3, s & 1);
    }

    // D layout: row=(lane>>4)*4+q, col=lane&15 (m89)
    const int orow0 = row0 + (lane >> 4) * 4;
    const int ocol0 = co0 + fr;
#pragma unroll
    for (int i = 0; i < 2; ++i)
#pragma unroll
        for (int j = 0; j < FN; ++j)
#pragma unroll
            for (int q = 0; q < 4; ++q) {
                int r = orow0 + i * 16 + q;
                int c = ocol0 + j * 16;
                if (r < N) {
                    float v = acc[i][j][q];
                    if constexpr (BFOUT) {
                        o[(size_t)r * COUT + c] = f2bf(v);
                    } else {
                        outf[(size_t)blockIdx.z * N * COUT + (size_t)r * COUT + c] = v;
                    }
                }
            }
}

// ------ deterministic fixed-order K-split reductions ------
__global__ __launch_bounds__(256) void reduce_f32(
    const float* __restrict__ p, float* __restrict__ out, int m4, int S)
{
    int i = blockIdx.x * 256 + threadIdx.x;
    if (i >= m4) return;
    const float4* p4 = reinterpret_cast<const float4*>(p);
    float4 a = p4[i];
    for (int s = 1; s < S; ++s) {
        float4 v = p4[(size_t)s * m4 + i];
        a.x += v.x; a.y += v.y; a.z += v.z; a.w += v.w;
    }
    reinterpret_cast<float4*>(out)[i] = a;
}
__global__ __launch_bounds__(256) void reduce_bf(
    const float* __restrict__ p, u16* __restrict__ o, int m, int S)
{
    int i = blockIdx.x * 256 + threadIdx.x;
    if (i >= m) return;
    float a = p[i];
    for (int s = 1; s < S; ++s) a += p[(size_t)s * m + i];
    o[i] = f2bf(a);
}

extern "C" void kernel_launch(void* const* d_in, const int* in_sizes, int n_in,
                              void* d_out, int out_size, void* d_ws, size_t ws_size,
                              hipStream_t stream)
{
    const float* feats = (const float*)d_in[0];
    const float* W1 = (const float*)d_in[1];
    const int*   nm1 = (const int*)d_in[2];
    const float* W2 = (const float*)d_in[3];
    const int*   nm2 = (const int*)d_in[4];
    const float* W3 = (const float*)d_in[5];
    const int*   nm3 = (const int*)d_in[6];
    const float* W4 = (const float*)d_in[7];
    const int*   nm4 = (const int*)d_in[8];
    const float* W5 = (const float*)d_in[9];
    const int*   nm5 = (const int*)d_in[10];

    const int M1 = in_sizes[2] / 27;   // ~360k
    const int M2 = in_sizes[4] / 27;   // ~196k
    const int M3 = in_sizes[6] / 27;   // ~33k
    const int M4 = in_sizes[8] / 27;   // ~4k
    const int M5 = in_sizes[10] / 27;  // ~512

    u16* x1 = (u16*)d_ws;                        // M1 x 16 bf16 (11.5 MB)
    u16* x2 = x1 + (size_t)M1 * 16;              // M2 x 32 (12.5 MB)
    u16* x3 = x2 + (size_t)M2 * 32;              // M3 x 64 (4.2 MB)
    u16* x4 = x3 + (size_t)M3 * 64;              // M4 x 128 (1.05 MB)
    u16* wt2 = x4 + (size_t)M4 * 128;            // 432*32 bf16
    u16* wt3 = wt2 + 432 * 32;                   // 864*64
    u16* wt4 = wt3 + 864 * 64;                   // 1728*128
    u16* wt5 = wt4 + 1728 * 128;                 // 3456*512
    // partials alias dead regions:
    // p4 on x1 (dead after L2): 4*M4*128*4B ≈ 8.4 MB <= M1*32B ≈ 11.5 MB ✓
    // p5 on x2 (dead after L3): 8*M5*512*4B ≈ 8.4 MB <= M2*64B ≈ 12.5 MB ✓
    float* p4 = (float*)x1;
    float* p5 = (float*)x2;

    wcast4<<<cdiv(432 * 32 + 864 * 64 + 1728 * 128 + 3456 * 512, 256), 256, 0, stream>>>(
        W2, W3, W4, W5, wt2, wt3, wt4, wt5);

    conv_l1<<<cdiv(M1, 256), 256, 0, stream>>>(feats, nm1, W1, x1, M1);

    // L2: 16 -> 32, FN=2 (COUT=32 caps tile), KPER=14
    conv_direct<16, 32, 2, 1, true>
        <<<dim3(cdiv(M2, 64), 1, 1), 128, 0, stream>>>(
            x1, nm2, wt2, nullptr, x2, M2);
    // L3: 32 -> 64, FN=4 (wave tile 32x64), KPER=27
    conv_direct<32, 64, 4, 1, true>
        <<<dim3(cdiv(M3, 64), 1, 1), 128, 0, stream>>>(
            x2, nm3, wt3, nullptr, x3, M3);
    // L4: 64 -> 128, FN=4, K-split 4 (KPER=14)
    conv_direct<64, 128, 4, 4, false>
        <<<dim3(cdiv(M4, 64), 2, 4), 128, 0, stream>>>(
            x3, nm4, wt4, p4, nullptr, M4);
    reduce_bf<<<cdiv(M4 * 128, 256), 256, 0, stream>>>(p4, x4, M4 * 128, 4);
    // L5: 128 -> 512, FN=4, K-split 8 (KPER=14)
    conv_direct<128, 512, 4, 8, false>
        <<<dim3(cdiv(M5, 64), 8, 8), 128, 0, stream>>>(
            x4, nm5, wt5, p5, nullptr, M5);
    reduce_f32<<<cdiv(M5 * 512 / 4, 256), 256, 0, stream>>>(p5, (float*)d_out, M5 * 512 / 4, 8);
}